// Round 9
// baseline (334.910 us; speedup 1.0000x reference)
//
#include <hip/hip_runtime.h>
#include <hip/hip_fp16.h>

#define NN 100000
#define NE 1600000
#define D  64

#define B1    256          // phase-1 blocks
#define CHUNK 6250         // NE / B1
#define BSH   9            // coarse bin = dst >> 9  (512 nodes per bin)
#define BMSK  511
#define NB    196          // ceil(NN / 512)
#define M     (NB * B1)    // hist entries = 50176 = 1024 * 49

#define GBLK  4096         // gather blocks
#define GW    (GBLK * 4)   // gather waves

// ---------- phase A: per-block coarse histogram (LDS atomics only) ----------
__global__ __launch_bounds__(256) void k_hist(const int* __restrict__ dst,
                                              int* __restrict__ hist) {
    __shared__ int h[NB];
    int t = threadIdx.x, blk = blockIdx.x;
    for (int i = t; i < NB; i += 256) h[i] = 0;
    __syncthreads();
    int e0 = blk * CHUNK;
    for (int e = e0 + t; e < e0 + CHUNK; e += 256)
        atomicAdd(&h[dst[e] >> BSH], 1);
    __syncthreads();
    for (int i = t; i < NB; i += 256) hist[i * B1 + blk] = h[i];  // bin-major
}

// ---------- exclusive scan of the 50176-entry (bin-major) matrix ----------
__global__ __launch_bounds__(1024) void k_scan(int* __restrict__ hist) {
    __shared__ int ps[1024];
    int t = threadIdx.x;
    const int C = M / 1024;          // 49
    int base = t * C;
    int s = 0;
    for (int i = 0; i < C; ++i) s += hist[base + i];
    ps[t] = s;
    __syncthreads();
    for (int off = 1; off < 1024; off <<= 1) {
        int u = (t >= off) ? ps[t - off] : 0;
        __syncthreads();
        ps[t] += u;
        __syncthreads();
    }
    int run = ps[t] - s;             // exclusive prefix of this chunk
    for (int i = 0; i < C; ++i) { int c = hist[base + i]; hist[base + i] = run; run += c; }
}

// ---------- phase B: scatter packed (src<<9 | local) into bin-contig ebuf ----------
__global__ __launch_bounds__(256) void k_scatter1(
    const int* __restrict__ src, const int* __restrict__ dst,
    const int* __restrict__ hist, unsigned* __restrict__ ebuf)
{
    __shared__ int cur[NB];
    int t = threadIdx.x, blk = blockIdx.x;
    for (int i = t; i < NB; i += 256) cur[i] = hist[i * B1 + blk];
    __syncthreads();
    int e0 = blk * CHUNK;
    for (int e = e0 + t; e < e0 + CHUNK; e += 256) {
        int d = dst[e];
        int p = atomicAdd(&cur[d >> BSH], 1);            // LDS atomic
        ebuf[p] = ((unsigned)src[e] << BSH) | (unsigned)(d & BMSK);
    }
}

// ---------- phase C: per-bin exact CSR, all in LDS ----------
__global__ __launch_bounds__(256) void k_build(
    const int* __restrict__ hist, const unsigned* __restrict__ ebuf,
    int* __restrict__ rs, float* __restrict__ dinv, int* __restrict__ bucket)
{
    __shared__ int c[512];
    __shared__ int ps[256];
    int t = threadIdx.x, b = blockIdx.x;
    int e0 = hist[b * B1];
    int e1 = (b == NB - 1) ? NE : hist[(b + 1) * B1];
    c[t] = 0; c[t + 256] = 0;
    __syncthreads();
    for (int e = e0 + t; e < e1; e += 256)
        atomicAdd(&c[ebuf[e] & BMSK], 1);
    __syncthreads();
    int a = c[2 * t], d2 = c[2 * t + 1];
    ps[t] = a + d2;
    __syncthreads();
    for (int off = 1; off < 256; off <<= 1) {
        int u = (t >= off) ? ps[t - off] : 0;
        __syncthreads();
        ps[t] += u;
        __syncthreads();
    }
    int ex = ps[t] - (a + d2);       // exclusive over pairs
    int p0 = e0 + ex, p1 = e0 + ex + a;
    int node0 = (b << BSH) + 2 * t, node1 = node0 + 1;
    if (node0 < NN) { rs[node0] = p0; dinv[node0] = rsqrtf((float)(a + 1)); }
    if (node1 < NN) { rs[node1] = p1; dinv[node1] = rsqrtf((float)(d2 + 1)); }
    if (b == NB - 1 && t == 0) rs[NN] = NE;
    __syncthreads();
    c[2 * t] = p0; c[2 * t + 1] = p1;  // cursors
    __syncthreads();
    for (int e = e0 + t; e < e1; e += 256) {
        unsigned u = ebuf[e];
        int p = atomicAdd(&c[u & BMSK], 1);              // LDS atomic
        bucket[p] = (int)(u >> BSH);
    }
}

// ---------- GEMM 1: g = half(x @ Wg * dinv) ----------
__global__ __launch_bounds__(256) void k_mm1(
    const float* __restrict__ x, const float* __restrict__ Wg,
    const float* __restrict__ dinv, __half* __restrict__ g)
{
    int lane = threadIdx.x & 63;
    int wid = blockIdx.x * 4 + (threadIdx.x >> 6);
    int nwaves = gridDim.x * 4;
    float w[D];
#pragma unroll
    for (int k = 0; k < D; ++k) w[k] = Wg[k * D + lane];
    for (int n0 = wid; n0 < NN; n0 += nwaves) {
        int n = __builtin_amdgcn_readfirstlane(n0);
        const float4* xr = (const float4*)(x + (long)n * D);
        float acc = 0.f;
#pragma unroll
        for (int k4 = 0; k4 < D / 4; ++k4) {
            float4 v = xr[k4];
            acc = fmaf(v.x, w[4 * k4 + 0], acc);
            acc = fmaf(v.y, w[4 * k4 + 1], acc);
            acc = fmaf(v.z, w[4 * k4 + 2], acc);
            acc = fmaf(v.w, w[4 * k4 + 3], acc);
        }
        g[(long)n * D + lane] = __float2half(acc * dinv[n]);
    }
}

// ---------- gather + fused pos-GEMM ----------
// Grid-stride wave-per-node. Quarter q (16 lanes) walks edges r0+q, +4, ...;
// lane reads one uint2 = 4 halves of the 128B g row -> 4 latency chains per
// wave. After xor-reduction lane g (g<16) holds granule g's quad; a shfl
// redistributes so lane l has feature l. Base = pos@Wp + bg + bp computed
// with Wp columns held in 64 VGPRs (loaded once per wave). out written once.
__device__ __forceinline__ float4 h4_to_f4(uint2 u) {
    __half2 a = *(__half2*)&u.x;
    __half2 b = *(__half2*)&u.y;
    float4 r;
    r.x = __low2float(a); r.y = __high2float(a);
    r.z = __low2float(b); r.w = __high2float(b);
    return r;
}

__global__ __launch_bounds__(256) void k_gather(
    const int* __restrict__ rs, const int* __restrict__ bucket,
    const float* __restrict__ dinv, const __half* __restrict__ g,
    const float* __restrict__ pos, const float* __restrict__ Wp,
    const float* __restrict__ bg, const float* __restrict__ bp,
    float* __restrict__ out)
{
    int lane = threadIdx.x & 63;
    int wid  = blockIdx.x * 4 + (threadIdx.x >> 6);
    int q = lane >> 4, f = lane & 15;

    float w[D];
#pragma unroll
    for (int k = 0; k < D; ++k) w[k] = Wp[k * D + lane];
    float bsum = bg[lane] + bp[lane];

    const uint2* gb = (const uint2*)g;   // 8B = half4 granules; row = 16 granules

    for (int n0 = wid; n0 < NN; n0 += GW) {
        int n = __builtin_amdgcn_readfirstlane(n0);
        int r0 = rs[n], r1 = rs[n + 1];

        float4 acc = make_float4(0.f, 0.f, 0.f, 0.f);
        for (int e = r0 + q; e < r1; e += 4) {
            int s = bucket[e];
            float4 v = h4_to_f4(gb[((long)s << 4) + f]);
            acc.x += v.x; acc.y += v.y; acc.z += v.z; acc.w += v.w;
        }
#pragma unroll
        for (int mask = 16; mask <= 32; mask <<= 1) {
            acc.x += __shfl_xor(acc.x, mask);
            acc.y += __shfl_xor(acc.y, mask);
            acc.z += __shfl_xor(acc.z, mask);
            acc.w += __shfl_xor(acc.w, mask);
        }
        // lane l wants component (l&3) of granule (l>>2); granule g's sum is
        // in lane g after the symmetric xor reduction.
        int srcl = lane >> 2;
        float v0 = __shfl(acc.x, srcl), v1 = __shfl(acc.y, srcl);
        float v2 = __shfl(acc.z, srcl), v3 = __shfl(acc.w, srcl);
        float agg = (lane & 2) ? ((lane & 1) ? v3 : v2)
                               : ((lane & 1) ? v1 : v0);

        float self = __half2float(g[(long)n * D + lane]);

        const float4* pr = (const float4*)(pos + (long)n * D);
        float base = bsum;
#pragma unroll
        for (int k4 = 0; k4 < D / 4; ++k4) {
            float4 v = pr[k4];
            base = fmaf(v.x, w[4 * k4 + 0], base);
            base = fmaf(v.y, w[4 * k4 + 1], base);
            base = fmaf(v.z, w[4 * k4 + 2], base);
            base = fmaf(v.w, w[4 * k4 + 3], base);
        }
        out[(long)n * D + lane] = base + (agg + self) * dinv[n];
    }
}

extern "C" void kernel_launch(void* const* d_in, const int* in_sizes, int n_in,
                              void* d_out, int out_size, void* d_ws, size_t ws_size,
                              hipStream_t stream) {
    const float* x   = (const float*)d_in[0];
    const int*   ei  = (const int*)d_in[1];   // [2, NE] int32
    const float* pos = (const float*)d_in[2];
    const float* Wg  = (const float*)d_in[3];
    const float* bg  = (const float*)d_in[4];
    const float* Wp  = (const float*)d_in[5];
    const float* bp  = (const float*)d_in[6];
    float* out = (float*)d_out;

    const int* src = ei;
    const int* dst = ei + NE;

    // ws: hist[M] | ebuf[NE] u32 | bucket[NE] | rs[NN+4] | dinv[NN] | g[NN*D] half
    int*      hist   = (int*)d_ws;
    unsigned* ebuf   = (unsigned*)(hist + M);
    int*      bucket = (int*)(ebuf + NE);
    int*      rs     = bucket + NE;
    float*    dinv   = (float*)(rs + NN + 4);
    __half*   g      = (__half*)(dinv + NN);

    hipLaunchKernelGGL(k_hist,     dim3(B1),   dim3(256),  0, stream, dst, hist);
    hipLaunchKernelGGL(k_scan,     dim3(1),    dim3(1024), 0, stream, hist);
    hipLaunchKernelGGL(k_scatter1, dim3(B1),   dim3(256),  0, stream, src, dst, hist, ebuf);
    hipLaunchKernelGGL(k_build,    dim3(NB),   dim3(256),  0, stream, hist, ebuf, rs, dinv, bucket);
    hipLaunchKernelGGL(k_mm1,      dim3(512),  dim3(256),  0, stream, x, Wg, dinv, g);
    hipLaunchKernelGGL(k_gather,   dim3(GBLK), dim3(256),  0, stream,
                       rs, bucket, dinv, g, pos, Wp, bg, bp, out);
}